// Round 17
// baseline (314.936 us; speedup 1.0000x reference)
//
#include <hip/hip_runtime.h>
#include <math.h>

#define NH   16
#define HD   64
#define HIDN 1024
#define NB   2
#define SEQ  2048
#define ROWS (NB*SEQ)   // 4096
#define BH   (NB*NH)    // 32

typedef __attribute__((ext_vector_type(8))) short bf16x8;
typedef __attribute__((ext_vector_type(8))) _Float16 f16x8;
typedef __attribute__((ext_vector_type(4))) float f32x4;
typedef __attribute__((ext_vector_type(2))) float f32x2;
typedef _Float16 f16;

typedef const __attribute__((address_space(1))) void GV;
typedef __attribute__((address_space(3))) void LV;
__device__ __forceinline__ void glds16(const void* g, void* l) {
    __builtin_amdgcn_global_load_lds((GV*)g, (LV*)l, 16, 0, 0);
}

__device__ __forceinline__ unsigned short f2bf(float f) {
    unsigned u = __float_as_uint(f);
    u += 0x7FFF + ((u >> 16) & 1);          // RNE
    return (unsigned short)(u >> 16);
}
__device__ __forceinline__ bf16x8 ldfrag(const unsigned short* p) {
    return *(const bf16x8*)p;
}
__device__ __forceinline__ f16x8 ldfragh(const f16* p) {
    return *(const f16x8*)p;
}
__device__ __forceinline__ f32x4 mfma16(bf16x8 a, bf16x8 b, f32x4 c) {
    return __builtin_amdgcn_mfma_f32_16x16x32_bf16(a, b, c, 0, 0, 0);
}
__device__ __forceinline__ f32x4 mfma16h(f16x8 a, f16x8 b, f32x4 c) {
    return __builtin_amdgcn_mfma_f32_16x16x32_f16(a, b, c, 0, 0, 0);
}

// w = (1 + acos(c))^-65 for a PAIR of scores. acos(1-u) ~ sqrt(u)*P4(u)
// (baseline poly, clang emits v_pk_*_f32); pow via rcp + 6 squarings.
// 2 trans/score (sqrt, rcp) vs 3 (sqrt, log, exp) — trans pipe is ~80% of
// the score phase. Round-3's regression was at 2 chains/nt; round-16
// structure has 4 independent chains/nt so the rcp chain issue-overlaps.
// This exact chain passed correctness in round 3 (absmax 0.0156).
__device__ __forceinline__ f32x2 pow65_pair(float c0, float c1) {
    f32x2 u = { fmaxf(1.0f - c0, 0.0f), fmaxf(1.0f - c1, 0.0f) };
    f32x2 s = { __builtin_amdgcn_sqrtf(u.x), __builtin_amdgcn_sqrtf(u.y) };
    f32x2 p = u * 2.68532e-3f + 7.89259e-3f;
    p = u * p + 2.6516504e-2f;
    p = u * p + 1.1785113e-1f;
    p = u * p + 1.4142136f;
    f32x2 t = s * p + 1.0f;                         // 1+g
    f32x2 y = { __builtin_amdgcn_rcpf(t.x), __builtin_amdgcn_rcpf(t.y) };
    f32x2 y2  = y  * y;
    f32x2 y4  = y2 * y2;
    f32x2 y8  = y4 * y4;
    f32x2 y16 = y8 * y8;
    f32x2 y32 = y16 * y16;
    f32x2 y64 = y32 * y32;
    return y64 * y;                                 // y^65
}
// pack two f32 to 2x bf16 RTZ (matches baseline's num/den bias cancellation)
__device__ __forceinline__ unsigned packbf(f32x2 w) {
    return (__float_as_uint(w.x) >> 16) | (__float_as_uint(w.y) & 0xffff0000u);
}

// ---------------- f32 -> f16 convert (n % 8 == 0) ---------------------------
__global__ __launch_bounds__(256)
void conv_f16(const float* __restrict__ src, f16* __restrict__ dst) {
    int i = (blockIdx.x * 256 + threadIdx.x) * 8;
    float4 a = *(const float4*)(src + i);
    float4 b = *(const float4*)(src + i + 4);
    f16x8 o = { (f16)a.x, (f16)a.y, (f16)a.z, (f16)a.w,
                (f16)b.x, (f16)b.y, (f16)b.z, (f16)b.w };
    *(f16x8*)(dst + i) = o;
}

// -------- fp16 MFMA NT GEMM, m97-style global_load_lds staging --------------
__global__ __launch_bounds__(256)
void gemm_nt_f16(const f16* __restrict__ A, const f16* __restrict__ B,
                 const float* __restrict__ bias, float* __restrict__ C,
                 int M, int N, int K)
{
    __shared__ f16 As[128 * 32];
    __shared__ f16 Bs[128 * 32];
    const int tid = threadIdx.x;
    const int lane = tid & 63, w = tid >> 6;
    const int ln = lane & 15, lq = lane >> 4;
    const int wm = (w >> 1) * 64, wn = (w & 1) * 64;
    const int m0 = blockIdx.x * 128, n0 = blockIdx.y * 128;

    const int grow = lane >> 2;        // 0..15
    const int gcol = (lane & 3) * 8;   // f16 offset
    const f16* Ab = A + (size_t)(m0 + w * 32 + grow) * K + gcol;
    const f16* Bb = B + (size_t)(n0 + w * 32 + grow) * K + gcol;
    f16* Asw = As + (w * 32) * 32;
    f16* Bsw = Bs + (w * 32) * 32;

    f32x4 acc[4][4];
    #pragma unroll
    for (int i = 0; i < 4; ++i)
        #pragma unroll
        for (int j = 0; j < 4; ++j) acc[i][j] = (f32x4){0.f, 0.f, 0.f, 0.f};

    for (int kc = 0; kc < K; kc += 32) {
        __syncthreads();
        #pragma unroll
        for (int i = 0; i < 2; ++i) {
            glds16(Ab + (size_t)(i * 16) * K + kc, Asw + (i * 16) * 32);
            glds16(Bb + (size_t)(i * 16) * K + kc, Bsw + (i * 16) * 32);
        }
        __syncthreads();
        f16x8 af[4], bf[4];
        #pragma unroll
        for (int i = 0; i < 4; ++i)
            af[i] = *(const f16x8*)&As[(wm + i * 16 + ln) * 32 + lq * 8];
        #pragma unroll
        for (int j = 0; j < 4; ++j)
            bf[j] = *(const f16x8*)&Bs[(wn + j * 16 + ln) * 32 + lq * 8];
        #pragma unroll
        for (int i = 0; i < 4; ++i)
            #pragma unroll
            for (int j = 0; j < 4; ++j)
                acc[i][j] = mfma16h(af[i], bf[j], acc[i][j]);
    }

    #pragma unroll
    for (int i = 0; i < 4; ++i) {
        #pragma unroll
        for (int j = 0; j < 4; ++j) {
            int colIdx = n0 + wn + j * 16 + ln;
            float bs = bias[colIdx];
            #pragma unroll
            for (int r = 0; r < 4; ++r) {
                int row = m0 + wm + i * 16 + lq * 4 + r;
                C[(size_t)row * N + colIdx] = acc[i][j][r] + bs;
            }
        }
    }
}

// -------- qkv GEMM with FUSED epilogues: q/k L2-normalize, v transpose ------
__global__ __launch_bounds__(256)
void gemm_qkv_f16(const f16* __restrict__ A, const f16* __restrict__ B,
                  const float* __restrict__ bias,
                  f16* __restrict__ qf, f16* __restrict__ kfo,
                  unsigned short* __restrict__ vth)
{
    const int K = HIDN;
    __shared__ f16 As[128 * 32];
    __shared__ f16 Bs[128 * 32];
    __shared__ __align__(16) unsigned short Vscr[4][16 * 72];  // 9216 B
    const int tid = threadIdx.x;
    const int lane = tid & 63, w = tid >> 6;
    const int ln = lane & 15, lq = lane >> 4;
    const int wm = (w >> 1) * 64, wn = (w & 1) * 64;
    const int m0 = blockIdx.x * 128, n0 = blockIdx.y * 128;

    const int grow = lane >> 2;        // 0..15
    const int gcol = (lane & 3) * 8;   // f16 offset
    const f16* Ab = A + (size_t)(m0 + w * 32 + grow) * K + gcol;
    const f16* Bb = B + (size_t)(n0 + w * 32 + grow) * K + gcol;
    f16* Asw = As + (w * 32) * 32;
    f16* Bsw = Bs + (w * 32) * 32;

    f32x4 acc[4][4];
    #pragma unroll
    for (int i = 0; i < 4; ++i)
        #pragma unroll
        for (int j = 0; j < 4; ++j) acc[i][j] = (f32x4){0.f, 0.f, 0.f, 0.f};

    for (int kc = 0; kc < K; kc += 32) {
        __syncthreads();
        #pragma unroll
        for (int i = 0; i < 2; ++i) {
            glds16(Ab + (size_t)(i * 16) * K + kc, Asw + (i * 16) * 32);
            glds16(Bb + (size_t)(i * 16) * K + kc, Bsw + (i * 16) * 32);
        }
        __syncthreads();
        f16x8 af[4], bf[4];
        #pragma unroll
        for (int i = 0; i < 4; ++i)
            af[i] = *(const f16x8*)&As[(wm + i * 16 + ln) * 32 + lq * 8];
        #pragma unroll
        for (int j = 0; j < 4; ++j)
            bf[j] = *(const f16x8*)&Bs[(wn + j * 16 + ln) * 32 + lq * 8];
        #pragma unroll
        for (int i = 0; i < 4; ++i)
            #pragma unroll
            for (int j = 0; j < 4; ++j)
                acc[i][j] = mfma16h(af[i], bf[j], acc[i][j]);
    }

    const int cbase = n0 + wn;          // 64-aligned head base
    float bs[4];
    #pragma unroll
    for (int j = 0; j < 4; ++j) bs[j] = bias[cbase + j * 16 + ln];

    if (cbase < 2 * HIDN) {
        // ---- q or k head: normalize + f16 store, no f32 round-trip ----
        f16* dst = (cbase < HIDN) ? qf : kfo;
        int h = (cbase & (HIDN - 1)) >> 6;
        #pragma unroll
        for (int i = 0; i < 4; ++i) {
            #pragma unroll
            for (int r = 0; r < 4; ++r) {
                float x0 = acc[i][0][r] + bs[0];
                float x1 = acc[i][1][r] + bs[1];
                float x2 = acc[i][2][r] + bs[2];
                float x3 = acc[i][3][r] + bs[3];
                float ss = x0 * x0 + x1 * x1 + x2 * x2 + x3 * x3;
                ss += __shfl_xor(ss, 1);
                ss += __shfl_xor(ss, 2);
                ss += __shfl_xor(ss, 4);
                ss += __shfl_xor(ss, 8);
                float inv = 1.0f / fmaxf(sqrtf(ss), 1e-12f);
                int row = m0 + wm + i * 16 + lq * 4 + r;
                int b = row >> 11, s = row & 2047;
                size_t base = ((size_t)((b * NH + h) * SEQ + s)) * HD;
                dst[base + 0 * 16 + ln] = (f16)(x0 * inv);
                dst[base + 1 * 16 + ln] = (f16)(x1 * inv);
                dst[base + 2 * 16 + ln] = (f16)(x2 * inv);
                dst[base + 3 * 16 + ln] = (f16)(x3 * inv);
            }
        }
    } else {
        // ---- v head: bf16 RNE, LDS-transposed, coalesced store ----
        int h = (cbase - 2 * HIDN) >> 6;
        int row0 = m0 + wm;
        int b = row0 >> 11;
        int s0 = row0 & 2047;
        size_t vbase = (size_t)(b * NH + h) * HD * SEQ;
        unsigned short* scr = Vscr[w];
        const int dd = lane >> 2, sseg = (lane & 3) * 16;
        #pragma unroll
        for (int j = 0; j < 4; ++j) {
            #pragma unroll
            for (int i = 0; i < 4; ++i) {
                unsigned short hi[4];
                #pragma unroll
                for (int r = 0; r < 4; ++r)
                    hi[r] = f2bf(acc[i][j][r] + bs[j]);
                *(uint2*)&scr[ln * 72 + i * 16 + lq * 4] = *(uint2*)hi;
            }
            // same-wave LDS: in-order pipe; compiler inserts lgkmcnt waits
            uint4 v0 = *(uint4*)&scr[dd * 72 + sseg];
            uint4 v1 = *(uint4*)&scr[dd * 72 + sseg + 8];
            size_t o = vbase + (size_t)(j * 16 + dd) * SEQ + s0 + sseg;
            *(uint4*)&vth[o]     = v0;
            *(uint4*)&vth[o + 8] = v1;
        }
    }
}

// KSTR=72 f16 -> 144 B row stride: 16B-aligned (b128-clean), 2-way bank
// aliasing only (free).
#define KSTR 72

// ------- partial col sums, s-split x4, 32 t-rows/wave (2 K reg sets) --------
__global__ __launch_bounds__(256)
void col_sum_f16(const f16* __restrict__ qf, const f16* __restrict__ kf,
                 float* __restrict__ colp)
{
    __shared__ __align__(16) f16 Qs[64 * KSTR];
    int bh = blockIdx.y;
    int tid = threadIdx.x, w = tid >> 6, lane = tid & 63, ln = lane & 15, lq = lane >> 4;
    int m0 = blockIdx.x * 128 + w * 32;         // this wave's 32 t-rows
    const int st0 = blockIdx.z * (SEQ / 256);   // first s-tile (8 per quarter)
    const f16* qb = qf + (size_t)bh * SEQ * HD;
    const int sr = tid >> 3;          // tile row 0..31
    const int sc = (tid & 7) * 8;     // f16 col offset

    size_t rowK0 = ((size_t)bh * SEQ + m0 + ln) * HD;
    size_t rowK1 = ((size_t)bh * SEQ + m0 + 16 + ln) * HD;
    f16x8 kf0 = ldfragh(kf + rowK0 + lq * 8), kf1 = ldfragh(kf + rowK0 + 32 + lq * 8);
    f16x8 kf2 = ldfragh(kf + rowK1 + lq * 8), kf3 = ldfragh(kf + rowK1 + 32 + lq * 8);

    uint4 qa = *(const uint4*)(qb + (size_t)(st0 * 64 + sr) * HD + sc);
    uint4 qc = *(const uint4*)(qb + (size_t)(st0 * 64 + sr + 32) * HD + sc);

    f32x2 ca01 = {0.f, 0.f}, ca23 = {0.f, 0.f};
    f32x2 cb01 = {0.f, 0.f}, cb23 = {0.f, 0.f};
    #pragma unroll 1
    for (int st = st0; st < st0 + SEQ / 256; ++st) {
        __syncthreads();
        *(uint4*)&Qs[sr * KSTR + sc] = qa;
        *(uint4*)&Qs[(sr + 32) * KSTR + sc] = qc;
        int sn = (st + 1 < st0 + SEQ / 256) ? (st + 1) * 64 : st0 * 64;
        qa = *(const uint4*)(qb + (size_t)(sn + sr) * HD + sc);
        qc = *(const uint4*)(qb + (size_t)(sn + sr + 32) * HD + sc);
        __syncthreads();
        #pragma unroll
        for (int nt = 0; nt < 4; ++nt) {
            const f16* qp = &Qs[(nt * 16 + ln) * KSTR + lq * 8];
            f16x8 qfa = *(const f16x8*)qp, qfc = *(const f16x8*)(qp + 32);
            f32x4 s0 = {0.f, 0.f, 0.f, 0.f};
            s0 = mfma16h(kf0, qfa, s0);
            s0 = mfma16h(kf1, qfc, s0);
            f32x4 s1 = {0.f, 0.f, 0.f, 0.f};
            s1 = mfma16h(kf2, qfa, s1);
            s1 = mfma16h(kf3, qfc, s1);
            ca01 += pow65_pair(s0[0], s0[1]);
            ca23 += pow65_pair(s0[2], s0[3]);
            cb01 += pow65_pair(s1[0], s1[1]);
            cb23 += pow65_pair(s1[2], s1[3]);
        }
    }
    float cacc[2][4] = { {ca01.x, ca01.y, ca23.x, ca23.y},
                         {cb01.x, cb01.y, cb23.x, cb23.y} };
    #pragma unroll
    for (int hs = 0; hs < 2; ++hs) {
        #pragma unroll
        for (int r = 0; r < 4; ++r) {
            float v = cacc[hs][r];
            v += __shfl_xor(v, 1); v += __shfl_xor(v, 2);
            v += __shfl_xor(v, 4); v += __shfl_xor(v, 8);
            if (ln == 0)
                colp[(size_t)blockIdx.z * BH * SEQ + (size_t)bh * SEQ
                     + m0 + hs * 16 + lq * 4 + r] = v;
        }
    }
}

// ------- col finalize: cl = rsqrt(sum of 4 partials) = colsum^-0.5 ----------
__global__ __launch_bounds__(256)
void col_finalize(const float* __restrict__ colp, float* __restrict__ col)
{
    int i = (blockIdx.x * 256 + threadIdx.x) * 4;
    float4 a = *(const float4*)&colp[i];
    float4 b = *(const float4*)&colp[(size_t)BH * SEQ + i];
    float4 c = *(const float4*)&colp[2 * (size_t)BH * SEQ + i];
    float4 d = *(const float4*)&colp[3 * (size_t)BH * SEQ + i];
    float4 o;
    o.x = __builtin_amdgcn_rsqf(a.x + b.x + c.x + d.x);
    o.y = __builtin_amdgcn_rsqf(a.y + b.y + c.y + d.y);
    o.z = __builtin_amdgcn_rsqf(a.z + b.z + c.z + d.z);
    o.w = __builtin_amdgcn_rsqf(a.w + b.w + c.w + d.w);
    *(float4*)&col[i] = o;
}

// ------- attention, t-split x2, 32 s-rows/wave: K/V LDS reads reused 2x -----
// w = (1+g)^-65 * cl[t], cl = colsum^-0.5 (f32). Same math as exp2(-65l+lcl),
// 2 trans/score instead of 3. RTZ bf16 W path unchanged.
__global__ __launch_bounds__(256, 4)
void attn_f16(const f16* __restrict__ qf, const f16* __restrict__ kf,
              const unsigned short* __restrict__ vth,
              const float* __restrict__ col,
              float* __restrict__ numb, float* __restrict__ denb)
{
    __shared__ __align__(16) f16 Ks[64 * KSTR];                // 9216 B
    __shared__ __align__(16) unsigned short Vs[64 * KSTR];     // 9216 B
    __shared__ __align__(16) unsigned short Ws[4][32 * KSTR];  // 18432 B
    __shared__ __align__(16) float lcls[64];                   // 256 B
    int bh = blockIdx.y;
    int b = bh >> 4, h = bh & 15;
    int tid = threadIdx.x, w = tid >> 6, lane = tid & 63, ln = lane & 15, lq = lane >> 4;
    int m0 = blockIdx.x * 128 + w * 32;
    const int th = blockIdx.z;
    const int tb = th * (SEQ / 2);              // first t of this half
    unsigned short* ws = Ws[w];

    const f16* kb = kf + (size_t)bh * SEQ * HD;
    const unsigned short* vb = vth + (size_t)bh * HD * SEQ;
    const float* cb = col + (size_t)bh * SEQ;

    const int sr = tid >> 3;
    const int sc = (tid & 7) * 8;

    size_t rowQ0 = ((size_t)bh * SEQ + m0 + ln) * HD;
    size_t rowQ1 = ((size_t)bh * SEQ + m0 + 16 + ln) * HD;
    f16x8 qf0 = ldfragh(qf + rowQ0 + lq * 8), qf1 = ldfragh(qf + rowQ0 + 32 + lq * 8);
    f16x8 qf2 = ldfragh(qf + rowQ1 + lq * 8), qf3 = ldfragh(qf + rowQ1 + 32 + lq * 8);

    bf16x8 ones;
    #pragma unroll
    for (int i = 0; i < 8; ++i) ones[i] = (short)0x3F80;  // bf16 1.0

    f32x4 num[2][4];
    #pragma unroll
    for (int hs = 0; hs < 2; ++hs)
        #pragma unroll
        for (int nt = 0; nt < 4; ++nt) num[hs][nt] = (f32x4){0.f, 0.f, 0.f, 0.f};
    f32x4 den[2] = { {0.f, 0.f, 0.f, 0.f}, {0.f, 0.f, 0.f, 0.f} };

    uint4 ka = *(const uint4*)(kb + (size_t)(tb + sr) * HD + sc);
    uint4 kc = *(const uint4*)(kb + (size_t)(tb + sr + 32) * HD + sc);
    uint4 va = *(const uint4*)(vb + (size_t)sr * SEQ + tb + sc);
    uint4 vc = *(const uint4*)(vb + (size_t)(sr + 32) * SEQ + tb + sc);
    float clv = (tid < 64) ? cb[tb + tid] : 0.f;

    #pragma unroll 1
    for (int tt = 0; tt < SEQ / 128; ++tt) {    // 16 tiles of 64 t
        __syncthreads();
        *(uint4*)&Ks[sr * KSTR + sc] = ka;
        *(uint4*)&Ks[(sr + 32) * KSTR + sc] = kc;
        *(uint4*)&Vs[sr * KSTR + sc] = va;
        *(uint4*)&Vs[(sr + 32) * KSTR + sc] = vc;
        if (tid < 64) lcls[tid] = clv;
        int tn = (tt + 1 < SEQ / 128) ? tb + (tt + 1) * 64 : tb;
        ka = *(const uint4*)(kb + (size_t)(tn + sr) * HD + sc);
        kc = *(const uint4*)(kb + (size_t)(tn + sr + 32) * HD + sc);
        va = *(const uint4*)(vb + (size_t)sr * SEQ + tn + sc);
        vc = *(const uint4*)(vb + (size_t)(sr + 32) * SEQ + tn + sc);
        clv = (tid < 64) ? cb[tn + tid] : 0.f;
        __syncthreads();

        // QK^T with A=K, B=Q: lane (ln,lq) -> s = m0+hs*16+ln,
        // t = t0+nt*16+lq*4+r. One K frag read serves BOTH s-halves.
        #pragma unroll
        for (int nt = 0; nt < 4; ++nt) {
            const f16* kp = &Ks[(nt * 16 + ln) * KSTR + lq * 8];
            f16x8 kfa = *(const f16x8*)kp, kfc = *(const f16x8*)(kp + 32);
            float4 cl = *(const float4*)&lcls[nt * 16 + lq * 4];
            f32x4 s0 = {0.f, 0.f, 0.f, 0.f};
            s0 = mfma16h(kfa, qf0, s0);
            s0 = mfma16h(kfc, qf1, s0);
            f32x4 s1 = {0.f, 0.f, 0.f, 0.f};
            s1 = mfma16h(kfa, qf2, s1);
            s1 = mfma16h(kfc, qf3, s1);
            f32x2 w01 = pow65_pair(s0[0], s0[1]) * (f32x2){cl.x, cl.y};
            f32x2 w23 = pow65_pair(s0[2], s0[3]) * (f32x2){cl.z, cl.w};
            f32x2 x01 = pow65_pair(s1[0], s1[1]) * (f32x2){cl.x, cl.y};
            f32x2 x23 = pow65_pair(s1[2], s1[3]) * (f32x2){cl.z, cl.w};
            uint2 pw0, pw1;
            pw0.x = packbf(w01);
            pw0.y = packbf(w23);
            pw1.x = packbf(x01);
            pw1.y = packbf(x23);
            *(uint2*)(ws + ln * KSTR + nt * 16 + lq * 4) = pw0;
            *(uint2*)(ws + (16 + ln) * KSTR + nt * 16 + lq * 4) = pw1;
        }
        // W in A-layout [s-local 0..31][t]; den += W @ ones; num += W @ V.
        // One V frag read serves BOTH s-halves.
        bf16x8 wa00 = ldfrag(ws + ln * KSTR + lq * 8);
        bf16x8 wa01 = ldfrag(ws + ln * KSTR + 32 + lq * 8);
        bf16x8 wa10 = ldfrag(ws + (16 + ln) * KSTR + lq * 8);
        bf16x8 wa11 = ldfrag(ws + (16 + ln) * KSTR + 32 + lq * 8);
        den[0] = mfma16(wa00, ones, den[0]);
        den[0] = mfma16(wa01, ones, den[0]);
        den[1] = mfma16(wa10, ones, den[1]);
        den[1] = mfma16(wa11, ones, den[1]);
        #pragma unroll
        for (int nt = 0; nt < 4; ++nt) {
            const unsigned short* vp = &Vs[(nt * 16 + ln) * KSTR + lq * 8];
            bf16x8 v0 = *(const bf16x8*)vp, v1 = *(const bf16x8*)(vp + 32);
            num[0][nt] = mfma16(wa00, v0, num[0][nt]);
            num[0][nt] = mfma16(wa01, v1, num[0][nt]);
            num[1][nt] = mfma16(wa10, v0, num[1][nt]);
            num[1][nt] = mfma16(wa11, v1, num[1][nt]);
        }
    }

    // epilogue: partial sums to this half's buffers (disjoint across blocks)
    const size_t noff = (size_t)th * ROWS * HIDN;
    #pragma unroll
    for (int hs = 0; hs < 2; ++hs) {
        #pragma unroll
        for (int r = 0; r < 4; ++r) {
            int s = m0 + hs * 16 + lq * 4 + r;
            #pragma unroll
            for (int nt = 0; nt < 4; ++nt)
                numb[noff + ((size_t)(b * SEQ + s)) * HIDN + h * HD + nt * 16 + ln] =
                    num[hs][nt][r];
            if (ln == 0)
                denb[(size_t)th * BH * SEQ + (size_t)bh * SEQ + s] = den[hs][r];
        }
    }
}

// ------- ctx = f16((num0+num1) / max(den0+den1, eps)) -----------------------
__global__ __launch_bounds__(256)
void finalize_ctx(const float* __restrict__ numb, const float* __restrict__ denb,
                  f16* __restrict__ ctx)
{
    size_t i = ((size_t)blockIdx.x * 256 + threadIdx.x) * 8;
    int row = (int)(i >> 10);               // / HIDN
    int cidx = (int)(i & (HIDN - 1));
    int b = row >> 11, s = row & 2047;
    int h = cidx >> 6;
    size_t di = (size_t)(b * NH + h) * SEQ + s;
    float d = denb[di] + denb[(size_t)BH * SEQ + di];
    float inv = 1.0f / fmaxf(d, 1e-12f);
    const float* n1 = numb + (size_t)ROWS * HIDN;
    float4 a0 = *(const float4*)&numb[i];
    float4 a1 = *(const float4*)&numb[i + 4];
    float4 b0 = *(const float4*)&n1[i];
    float4 b1 = *(const float4*)&n1[i + 4];
    f16x8 o = { (f16)((a0.x + b0.x) * inv), (f16)((a0.y + b0.y) * inv),
                (f16)((a0.z + b0.z) * inv), (f16)((a0.w + b0.w) * inv),
                (f16)((a1.x + b1.x) * inv), (f16)((a1.y + b1.y) * inv),
                (f16)((a1.z + b1.z) * inv), (f16)((a1.w + b1.w) * inv) };
    *(f16x8*)(ctx + i) = o;
}

extern "C" void kernel_launch(void* const* d_in, const int* in_sizes, int n_in,
                              void* d_out, int out_size, void* d_ws, size_t ws_size,
                              hipStream_t stream) {
    const float* x      = (const float*)d_in[0];
    const float* qkv_w  = (const float*)d_in[1];
    const float* qkv_b  = (const float*)d_in[2];
    const float* out_w  = (const float*)d_in[3];
    const float* out_b  = (const float*)d_in[4];
    float* out = (float*)d_out;

    const size_t NTT = (size_t)BH * SEQ * HD;             // 4.19M
    float* qkv = (float*)d_ws;                            // 12.58M f32 region
    // partial buffers live in the (now otherwise unused) qkv region:
    float* colp = qkv;                                    // 4 * BH*SEQ
    float* denb = qkv + 4 * (size_t)BH * SEQ;             // 2 * BH*SEQ
    float* numb = qkv + 6 * (size_t)BH * SEQ;             // 2 * ROWS*HIDN = 8.39M
    float* col = qkv + (size_t)ROWS * 3 * HIDN;           // holds cl
    f16* xh    = (f16*)(col + (size_t)BH * SEQ);
    f16* wqh   = xh + (size_t)ROWS * HIDN;
    f16* woh   = wqh + (size_t)3 * HIDN * HIDN;
    f16* ctxh  = woh + (size_t)HIDN * HIDN;
    f16* qfp   = ctxh + (size_t)ROWS * HIDN;
    f16* kfp   = qfp + NTT;
    unsigned short* vth = (unsigned short*)(kfp + NTT);

    conv_f16<<<ROWS*HIDN/2048, 256, 0, stream>>>(x, xh);
    conv_f16<<<3*HIDN*HIDN/2048, 256, 0, stream>>>(qkv_w, wqh);
    conv_f16<<<HIDN*HIDN/2048, 256, 0, stream>>>(out_w, woh);

    gemm_qkv_f16<<<dim3(ROWS/128, 3*HIDN/128), 256, 0, stream>>>(
        xh, wqh, qkv_b, qfp, kfp, vth);
    col_sum_f16<<<dim3(SEQ/128, BH, 4), 256, 0, stream>>>(qfp, kfp, colp);
    col_finalize<<<BH*SEQ/1024, 256, 0, stream>>>(colp, col);
    attn_f16<<<dim3(SEQ/128, BH, 2), 256, 0, stream>>>(qfp, kfp, vth, col,
                                                       numb, denb);
    finalize_ctx<<<ROWS*HIDN/2048, 256, 0, stream>>>(numb, denb, ctxh);
    gemm_nt_f16<<<dim3(ROWS/128, HIDN/128), 256, 0, stream>>>(
        ctxh, woh, out_b, out, ROWS, HIDN, HIDN);
}

// Round 18
// 297.689 us; speedup vs baseline: 1.0579x; 1.0579x over previous
//
#include <hip/hip_runtime.h>
#include <math.h>

#define NH   16
#define HD   64
#define HIDN 1024
#define NB   2
#define SEQ  2048
#define ROWS (NB*SEQ)   // 4096
#define BH   (NB*NH)    // 32

typedef __attribute__((ext_vector_type(8))) short bf16x8;
typedef __attribute__((ext_vector_type(8))) _Float16 f16x8;
typedef __attribute__((ext_vector_type(4))) float f32x4;
typedef __attribute__((ext_vector_type(2))) float f32x2;
typedef _Float16 f16;

typedef const __attribute__((address_space(1))) void GV;
typedef __attribute__((address_space(3))) void LV;
__device__ __forceinline__ void glds16(const void* g, void* l) {
    __builtin_amdgcn_global_load_lds((GV*)g, (LV*)l, 16, 0, 0);
}

__device__ __forceinline__ unsigned short f2bf(float f) {
    unsigned u = __float_as_uint(f);
    u += 0x7FFF + ((u >> 16) & 1);          // RNE
    return (unsigned short)(u >> 16);
}
__device__ __forceinline__ bf16x8 ldfrag(const unsigned short* p) {
    return *(const bf16x8*)p;
}
__device__ __forceinline__ f16x8 ldfragh(const f16* p) {
    return *(const f16x8*)p;
}
__device__ __forceinline__ f32x4 mfma16(bf16x8 a, bf16x8 b, f32x4 c) {
    return __builtin_amdgcn_mfma_f32_16x16x32_bf16(a, b, c, 0, 0, 0);
}
__device__ __forceinline__ f32x4 mfma16h(f16x8 a, f16x8 b, f32x4 c) {
    return __builtin_amdgcn_mfma_f32_16x16x32_f16(a, b, c, 0, 0, 0);
}

// l = log2(1 + acos(c)) for a PAIR of scores: packed full-rate poly
// (clang emits v_pk_*_f32), scalar transcendentals. acos(1-u) ~ sqrt(u)*P4(u).
// sqrt->log->exp is the measured optimum: rcp+squaring pow REGRESSED twice
// (r3 +9%, r17 +13%) — pk-muls displace VALU issue; log/exp run on the
// trans pipe concurrently with other waves' VALU work.
__device__ __forceinline__ f32x2 log2_1pacos_pair(float c0, float c1) {
    f32x2 u = { fmaxf(1.0f - c0, 0.0f), fmaxf(1.0f - c1, 0.0f) };
    f32x2 s = { __builtin_amdgcn_sqrtf(u.x), __builtin_amdgcn_sqrtf(u.y) };
    f32x2 p = u * 2.68532e-3f + 7.89259e-3f;
    p = u * p + 2.6516504e-2f;
    p = u * p + 1.1785113e-1f;
    p = u * p + 1.4142136f;
    f32x2 t = s * p + 1.0f;                         // 1+g
    return (f32x2){ __builtin_amdgcn_logf(t.x), __builtin_amdgcn_logf(t.y) };
}
// pack two f32 to 2x bf16 RTZ (matches baseline's num/den bias cancellation)
__device__ __forceinline__ unsigned packbf(f32x2 w) {
    return (__float_as_uint(w.x) >> 16) | (__float_as_uint(w.y) & 0xffff0000u);
}

// ---------------- f32 -> f16 convert (n % 8 == 0) ---------------------------
__global__ __launch_bounds__(256)
void conv_f16(const float* __restrict__ src, f16* __restrict__ dst) {
    int i = (blockIdx.x * 256 + threadIdx.x) * 8;
    float4 a = *(const float4*)(src + i);
    float4 b = *(const float4*)(src + i + 4);
    f16x8 o = { (f16)a.x, (f16)a.y, (f16)a.z, (f16)a.w,
                (f16)b.x, (f16)b.y, (f16)b.z, (f16)b.w };
    *(f16x8*)(dst + i) = o;
}

// -------- fp16 MFMA NT GEMM, m97-style global_load_lds staging --------------
__global__ __launch_bounds__(256)
void gemm_nt_f16(const f16* __restrict__ A, const f16* __restrict__ B,
                 const float* __restrict__ bias, float* __restrict__ C,
                 int M, int N, int K)
{
    __shared__ f16 As[128 * 32];
    __shared__ f16 Bs[128 * 32];
    const int tid = threadIdx.x;
    const int lane = tid & 63, w = tid >> 6;
    const int ln = lane & 15, lq = lane >> 4;
    const int wm = (w >> 1) * 64, wn = (w & 1) * 64;
    const int m0 = blockIdx.x * 128, n0 = blockIdx.y * 128;

    const int grow = lane >> 2;        // 0..15
    const int gcol = (lane & 3) * 8;   // f16 offset
    const f16* Ab = A + (size_t)(m0 + w * 32 + grow) * K + gcol;
    const f16* Bb = B + (size_t)(n0 + w * 32 + grow) * K + gcol;
    f16* Asw = As + (w * 32) * 32;
    f16* Bsw = Bs + (w * 32) * 32;

    f32x4 acc[4][4];
    #pragma unroll
    for (int i = 0; i < 4; ++i)
        #pragma unroll
        for (int j = 0; j < 4; ++j) acc[i][j] = (f32x4){0.f, 0.f, 0.f, 0.f};

    for (int kc = 0; kc < K; kc += 32) {
        __syncthreads();
        #pragma unroll
        for (int i = 0; i < 2; ++i) {
            glds16(Ab + (size_t)(i * 16) * K + kc, Asw + (i * 16) * 32);
            glds16(Bb + (size_t)(i * 16) * K + kc, Bsw + (i * 16) * 32);
        }
        __syncthreads();
        f16x8 af[4], bf[4];
        #pragma unroll
        for (int i = 0; i < 4; ++i)
            af[i] = *(const f16x8*)&As[(wm + i * 16 + ln) * 32 + lq * 8];
        #pragma unroll
        for (int j = 0; j < 4; ++j)
            bf[j] = *(const f16x8*)&Bs[(wn + j * 16 + ln) * 32 + lq * 8];
        #pragma unroll
        for (int i = 0; i < 4; ++i)
            #pragma unroll
            for (int j = 0; j < 4; ++j)
                acc[i][j] = mfma16h(af[i], bf[j], acc[i][j]);
    }

    #pragma unroll
    for (int i = 0; i < 4; ++i) {
        #pragma unroll
        for (int j = 0; j < 4; ++j) {
            int colIdx = n0 + wn + j * 16 + ln;
            float bs = bias[colIdx];
            #pragma unroll
            for (int r = 0; r < 4; ++r) {
                int row = m0 + wm + i * 16 + lq * 4 + r;
                C[(size_t)row * N + colIdx] = acc[i][j][r] + bs;
            }
        }
    }
}

// -------- qkv GEMM with FUSED epilogues: q/k L2-normalize, v transpose ------
// N=3*HIDN. Each wave's 64-col range is 64-aligned = exactly one head.
// q/k waves: full head-row lives in the wave's accs -> in-wave sumsq
// (in-reg over j + shfl_xor over ln) -> rsqrt -> f16 store to [BH][S][D].
// v waves: bf16 RNE, per-wave LDS bounce (dedicated Vscr slice, no barrier:
// same-wave in-order LDS) -> transposed COALESCED store to vth[bh][d][s].
__global__ __launch_bounds__(256)
void gemm_qkv_f16(const f16* __restrict__ A, const f16* __restrict__ B,
                  const float* __restrict__ bias,
                  f16* __restrict__ qf, f16* __restrict__ kfo,
                  unsigned short* __restrict__ vth)
{
    const int K = HIDN;
    __shared__ f16 As[128 * 32];
    __shared__ f16 Bs[128 * 32];
    __shared__ __align__(16) unsigned short Vscr[4][16 * 72];  // 9216 B
    const int tid = threadIdx.x;
    const int lane = tid & 63, w = tid >> 6;
    const int ln = lane & 15, lq = lane >> 4;
    const int wm = (w >> 1) * 64, wn = (w & 1) * 64;
    const int m0 = blockIdx.x * 128, n0 = blockIdx.y * 128;

    const int grow = lane >> 2;        // 0..15
    const int gcol = (lane & 3) * 8;   // f16 offset
    const f16* Ab = A + (size_t)(m0 + w * 32 + grow) * K + gcol;
    const f16* Bb = B + (size_t)(n0 + w * 32 + grow) * K + gcol;
    f16* Asw = As + (w * 32) * 32;
    f16* Bsw = Bs + (w * 32) * 32;

    f32x4 acc[4][4];
    #pragma unroll
    for (int i = 0; i < 4; ++i)
        #pragma unroll
        for (int j = 0; j < 4; ++j) acc[i][j] = (f32x4){0.f, 0.f, 0.f, 0.f};

    for (int kc = 0; kc < K; kc += 32) {
        __syncthreads();
        #pragma unroll
        for (int i = 0; i < 2; ++i) {
            glds16(Ab + (size_t)(i * 16) * K + kc, Asw + (i * 16) * 32);
            glds16(Bb + (size_t)(i * 16) * K + kc, Bsw + (i * 16) * 32);
        }
        __syncthreads();
        f16x8 af[4], bf[4];
        #pragma unroll
        for (int i = 0; i < 4; ++i)
            af[i] = *(const f16x8*)&As[(wm + i * 16 + ln) * 32 + lq * 8];
        #pragma unroll
        for (int j = 0; j < 4; ++j)
            bf[j] = *(const f16x8*)&Bs[(wn + j * 16 + ln) * 32 + lq * 8];
        #pragma unroll
        for (int i = 0; i < 4; ++i)
            #pragma unroll
            for (int j = 0; j < 4; ++j)
                acc[i][j] = mfma16h(af[i], bf[j], acc[i][j]);
    }

    const int cbase = n0 + wn;          // 64-aligned head base
    float bs[4];
    #pragma unroll
    for (int j = 0; j < 4; ++j) bs[j] = bias[cbase + j * 16 + ln];

    if (cbase < 2 * HIDN) {
        // ---- q or k head: normalize + f16 store, no f32 round-trip ----
        f16* dst = (cbase < HIDN) ? qf : kfo;
        int h = (cbase & (HIDN - 1)) >> 6;
        #pragma unroll
        for (int i = 0; i < 4; ++i) {
            #pragma unroll
            for (int r = 0; r < 4; ++r) {
                float x0 = acc[i][0][r] + bs[0];
                float x1 = acc[i][1][r] + bs[1];
                float x2 = acc[i][2][r] + bs[2];
                float x3 = acc[i][3][r] + bs[3];
                float ss = x0 * x0 + x1 * x1 + x2 * x2 + x3 * x3;
                ss += __shfl_xor(ss, 1);
                ss += __shfl_xor(ss, 2);
                ss += __shfl_xor(ss, 4);
                ss += __shfl_xor(ss, 8);
                float inv = 1.0f / fmaxf(sqrtf(ss), 1e-12f);
                int row = m0 + wm + i * 16 + lq * 4 + r;
                int b = row >> 11, s = row & 2047;
                size_t base = ((size_t)((b * NH + h) * SEQ + s)) * HD;
                dst[base + 0 * 16 + ln] = (f16)(x0 * inv);
                dst[base + 1 * 16 + ln] = (f16)(x1 * inv);
                dst[base + 2 * 16 + ln] = (f16)(x2 * inv);
                dst[base + 3 * 16 + ln] = (f16)(x3 * inv);
            }
        }
    } else {
        // ---- v head: bf16 RNE, LDS-transposed, coalesced store ----
        int h = (cbase - 2 * HIDN) >> 6;
        int row0 = m0 + wm;
        int b = row0 >> 11;
        int s0 = row0 & 2047;
        size_t vbase = (size_t)(b * NH + h) * HD * SEQ;
        unsigned short* scr = Vscr[w];
        const int dd = lane >> 2, sseg = (lane & 3) * 16;
        #pragma unroll
        for (int j = 0; j < 4; ++j) {
            #pragma unroll
            for (int i = 0; i < 4; ++i) {
                unsigned short hi[4];
                #pragma unroll
                for (int r = 0; r < 4; ++r)
                    hi[r] = f2bf(acc[i][j][r] + bs[j]);
                *(uint2*)&scr[ln * 72 + i * 16 + lq * 4] = *(uint2*)hi;
            }
            // same-wave LDS: in-order pipe; compiler inserts lgkmcnt waits
            uint4 v0 = *(uint4*)&scr[dd * 72 + sseg];
            uint4 v1 = *(uint4*)&scr[dd * 72 + sseg + 8];
            size_t o = vbase + (size_t)(j * 16 + dd) * SEQ + s0 + sseg;
            *(uint4*)&vth[o]     = v0;
            *(uint4*)&vth[o + 8] = v1;
        }
    }
}

// KSTR=72 f16 -> 144 B row stride: 16B-aligned (b128-clean), 2-way bank
// aliasing only (free).
#define KSTR 72

// ------- partial col sums, s-split x4, 32 t-rows/wave (2 K reg sets) --------
__global__ __launch_bounds__(256)
void col_sum_f16(const f16* __restrict__ qf, const f16* __restrict__ kf,
                 float* __restrict__ colp)
{
    __shared__ __align__(16) f16 Qs[64 * KSTR];
    int bh = blockIdx.y;
    int tid = threadIdx.x, w = tid >> 6, lane = tid & 63, ln = lane & 15, lq = lane >> 4;
    int m0 = blockIdx.x * 128 + w * 32;         // this wave's 32 t-rows
    const int st0 = blockIdx.z * (SEQ / 256);   // first s-tile (8 per quarter)
    const f16* qb = qf + (size_t)bh * SEQ * HD;
    const int sr = tid >> 3;          // tile row 0..31
    const int sc = (tid & 7) * 8;     // f16 col offset

    size_t rowK0 = ((size_t)bh * SEQ + m0 + ln) * HD;
    size_t rowK1 = ((size_t)bh * SEQ + m0 + 16 + ln) * HD;
    f16x8 kf0 = ldfragh(kf + rowK0 + lq * 8), kf1 = ldfragh(kf + rowK0 + 32 + lq * 8);
    f16x8 kf2 = ldfragh(kf + rowK1 + lq * 8), kf3 = ldfragh(kf + rowK1 + 32 + lq * 8);

    uint4 qa = *(const uint4*)(qb + (size_t)(st0 * 64 + sr) * HD + sc);
    uint4 qc = *(const uint4*)(qb + (size_t)(st0 * 64 + sr + 32) * HD + sc);

    f32x2 ca01 = {0.f, 0.f}, ca23 = {0.f, 0.f};
    f32x2 cb01 = {0.f, 0.f}, cb23 = {0.f, 0.f};
    #pragma unroll 1
    for (int st = st0; st < st0 + SEQ / 256; ++st) {
        __syncthreads();
        *(uint4*)&Qs[sr * KSTR + sc] = qa;
        *(uint4*)&Qs[(sr + 32) * KSTR + sc] = qc;
        int sn = (st + 1 < st0 + SEQ / 256) ? (st + 1) * 64 : st0 * 64;
        qa = *(const uint4*)(qb + (size_t)(sn + sr) * HD + sc);
        qc = *(const uint4*)(qb + (size_t)(sn + sr + 32) * HD + sc);
        __syncthreads();
        #pragma unroll
        for (int nt = 0; nt < 4; ++nt) {
            const f16* qp = &Qs[(nt * 16 + ln) * KSTR + lq * 8];
            f16x8 qfa = *(const f16x8*)qp, qfc = *(const f16x8*)(qp + 32);
            f32x4 s0 = {0.f, 0.f, 0.f, 0.f};
            s0 = mfma16h(kf0, qfa, s0);
            s0 = mfma16h(kf1, qfc, s0);
            f32x4 s1 = {0.f, 0.f, 0.f, 0.f};
            s1 = mfma16h(kf2, qfa, s1);
            s1 = mfma16h(kf3, qfc, s1);
            f32x2 la01 = log2_1pacos_pair(s0[0], s0[1]) * -65.0f;
            f32x2 la23 = log2_1pacos_pair(s0[2], s0[3]) * -65.0f;
            f32x2 lb01 = log2_1pacos_pair(s1[0], s1[1]) * -65.0f;
            f32x2 lb23 = log2_1pacos_pair(s1[2], s1[3]) * -65.0f;
            ca01 += (f32x2){ __builtin_amdgcn_exp2f(la01.x),
                             __builtin_amdgcn_exp2f(la01.y) };
            ca23 += (f32x2){ __builtin_amdgcn_exp2f(la23.x),
                             __builtin_amdgcn_exp2f(la23.y) };
            cb01 += (f32x2){ __builtin_amdgcn_exp2f(lb01.x),
                             __builtin_amdgcn_exp2f(lb01.y) };
            cb23 += (f32x2){ __builtin_amdgcn_exp2f(lb23.x),
                             __builtin_amdgcn_exp2f(lb23.y) };
        }
    }
    float cacc[2][4] = { {ca01.x, ca01.y, ca23.x, ca23.y},
                         {cb01.x, cb01.y, cb23.x, cb23.y} };
    #pragma unroll
    for (int hs = 0; hs < 2; ++hs) {
        #pragma unroll
        for (int r = 0; r < 4; ++r) {
            float v = cacc[hs][r];
            v += __shfl_xor(v, 1); v += __shfl_xor(v, 2);
            v += __shfl_xor(v, 4); v += __shfl_xor(v, 8);
            if (ln == 0)
                colp[(size_t)blockIdx.z * BH * SEQ + (size_t)bh * SEQ
                     + m0 + hs * 16 + lq * 4 + r] = v;
        }
    }
}

// ------- col finalize: lcl = -0.5*log2(sum of 4 partials) -------------------
__global__ __launch_bounds__(256)
void col_finalize(const float* __restrict__ colp, float* __restrict__ col)
{
    int i = (blockIdx.x * 256 + threadIdx.x) * 4;
    float4 a = *(const float4*)&colp[i];
    float4 b = *(const float4*)&colp[(size_t)BH * SEQ + i];
    float4 c = *(const float4*)&colp[2 * (size_t)BH * SEQ + i];
    float4 d = *(const float4*)&colp[3 * (size_t)BH * SEQ + i];
    float4 o;
    o.x = -0.5f * __builtin_amdgcn_logf(a.x + b.x + c.x + d.x);
    o.y = -0.5f * __builtin_amdgcn_logf(a.y + b.y + c.y + d.y);
    o.z = -0.5f * __builtin_amdgcn_logf(a.z + b.z + c.z + d.z);
    o.w = -0.5f * __builtin_amdgcn_logf(a.w + b.w + c.w + d.w);
    *(float4*)&col[i] = o;
}

// ------- attention, t-split x2, 32 s-rows/wave: K/V LDS reads reused 2x -----
// Round-11 structure (measured best: 86-87 us), unchanged.
__global__ __launch_bounds__(256, 4)
void attn_f16(const f16* __restrict__ qf, const f16* __restrict__ kf,
              const unsigned short* __restrict__ vth,
              const float* __restrict__ col,
              float* __restrict__ numb, float* __restrict__ denb)
{
    __shared__ __align__(16) f16 Ks[64 * KSTR];                // 9216 B
    __shared__ __align__(16) unsigned short Vs[64 * KSTR];     // 9216 B
    __shared__ __align__(16) unsigned short Ws[4][32 * KSTR];  // 18432 B
    __shared__ __align__(16) float lcls[64];                   // 256 B
    int bh = blockIdx.y;
    int b = bh >> 4, h = bh & 15;
    int tid = threadIdx.x, w = tid >> 6, lane = tid & 63, ln = lane & 15, lq = lane >> 4;
    int m0 = blockIdx.x * 128 + w * 32;
    const int th = blockIdx.z;
    const int tb = th * (SEQ / 2);              // first t of this half
    unsigned short* ws = Ws[w];

    const f16* kb = kf + (size_t)bh * SEQ * HD;
    const unsigned short* vb = vth + (size_t)bh * HD * SEQ;
    const float* cb = col + (size_t)bh * SEQ;

    const int sr = tid >> 3;
    const int sc = (tid & 7) * 8;

    size_t rowQ0 = ((size_t)bh * SEQ + m0 + ln) * HD;
    size_t rowQ1 = ((size_t)bh * SEQ + m0 + 16 + ln) * HD;
    f16x8 qf0 = ldfragh(qf + rowQ0 + lq * 8), qf1 = ldfragh(qf + rowQ0 + 32 + lq * 8);
    f16x8 qf2 = ldfragh(qf + rowQ1 + lq * 8), qf3 = ldfragh(qf + rowQ1 + 32 + lq * 8);

    bf16x8 ones;
    #pragma unroll
    for (int i = 0; i < 8; ++i) ones[i] = (short)0x3F80;  // bf16 1.0

    f32x4 num[2][4];
    #pragma unroll
    for (int hs = 0; hs < 2; ++hs)
        #pragma unroll
        for (int nt = 0; nt < 4; ++nt) num[hs][nt] = (f32x4){0.f, 0.f, 0.f, 0.f};
    f32x4 den[2] = { {0.f, 0.f, 0.f, 0.f}, {0.f, 0.f, 0.f, 0.f} };

    uint4 ka = *(const uint4*)(kb + (size_t)(tb + sr) * HD + sc);
    uint4 kc = *(const uint4*)(kb + (size_t)(tb + sr + 32) * HD + sc);
    uint4 va = *(const uint4*)(vb + (size_t)sr * SEQ + tb + sc);
    uint4 vc = *(const uint4*)(vb + (size_t)(sr + 32) * SEQ + tb + sc);
    float clv = (tid < 64) ? cb[tb + tid] : 0.f;

    #pragma unroll 1
    for (int tt = 0; tt < SEQ / 128; ++tt) {    // 16 tiles of 64 t
        __syncthreads();
        *(uint4*)&Ks[sr * KSTR + sc] = ka;
        *(uint4*)&Ks[(sr + 32) * KSTR + sc] = kc;
        *(uint4*)&Vs[sr * KSTR + sc] = va;
        *(uint4*)&Vs[(sr + 32) * KSTR + sc] = vc;
        if (tid < 64) lcls[tid] = clv;
        int tn = (tt + 1 < SEQ / 128) ? tb + (tt + 1) * 64 : tb;
        ka = *(const uint4*)(kb + (size_t)(tn + sr) * HD + sc);
        kc = *(const uint4*)(kb + (size_t)(tn + sr + 32) * HD + sc);
        va = *(const uint4*)(vb + (size_t)sr * SEQ + tn + sc);
        vc = *(const uint4*)(vb + (size_t)(sr + 32) * SEQ + tn + sc);
        clv = (tid < 64) ? cb[tn + tid] : 0.f;
        __syncthreads();

        // QK^T with A=K, B=Q: lane (ln,lq) -> s = m0+hs*16+ln,
        // t = t0+nt*16+lq*4+r. One K frag read serves BOTH s-halves.
        #pragma unroll
        for (int nt = 0; nt < 4; ++nt) {
            const f16* kp = &Ks[(nt * 16 + ln) * KSTR + lq * 8];
            f16x8 kfa = *(const f16x8*)kp, kfc = *(const f16x8*)(kp + 32);
            float4 cl = *(const float4*)&lcls[nt * 16 + lq * 4];
            f32x4 s0 = {0.f, 0.f, 0.f, 0.f};
            s0 = mfma16h(kfa, qf0, s0);
            s0 = mfma16h(kfc, qf1, s0);
            f32x4 s1 = {0.f, 0.f, 0.f, 0.f};
            s1 = mfma16h(kfa, qf2, s1);
            s1 = mfma16h(kfc, qf3, s1);
            f32x2 a01 = log2_1pacos_pair(s0[0], s0[1]) * -65.0f + (f32x2){cl.x, cl.y};
            f32x2 a23 = log2_1pacos_pair(s0[2], s0[3]) * -65.0f + (f32x2){cl.z, cl.w};
            f32x2 b01 = log2_1pacos_pair(s1[0], s1[1]) * -65.0f + (f32x2){cl.x, cl.y};
            f32x2 b23 = log2_1pacos_pair(s1[2], s1[3]) * -65.0f + (f32x2){cl.z, cl.w};
            uint2 pw0, pw1;
            pw0.x = packbf((f32x2){ __builtin_amdgcn_exp2f(a01.x),
                                    __builtin_amdgcn_exp2f(a01.y) });
            pw0.y = packbf((f32x2){ __builtin_amdgcn_exp2f(a23.x),
                                    __builtin_amdgcn_exp2f(a23.y) });
            pw1.x = packbf((f32x2){ __builtin_amdgcn_exp2f(b01.x),
                                    __builtin_amdgcn_exp2f(b01.y) });
            pw1.y = packbf((f32x2){ __builtin_amdgcn_exp2f(b23.x),
                                    __builtin_amdgcn_exp2f(b23.y) });
            *(uint2*)(ws + ln * KSTR + nt * 16 + lq * 4) = pw0;
            *(uint2*)(ws + (16 + ln) * KSTR + nt * 16 + lq * 4) = pw1;
        }
        // W in A-layout [s-local 0..31][t]; den += W @ ones; num += W @ V.
        // One V frag read serves BOTH s-halves.
        bf16x8 wa00 = ldfrag(ws + ln * KSTR + lq * 8);
        bf16x8 wa01 = ldfrag(ws + ln * KSTR + 32 + lq * 8);
        bf16x8 wa10 = ldfrag(ws + (16 + ln) * KSTR + lq * 8);
        bf16x8 wa11 = ldfrag(ws + (16 + ln) * KSTR + 32 + lq * 8);
        den[0] = mfma16(wa00, ones, den[0]);
        den[0] = mfma16(wa01, ones, den[0]);
        den[1] = mfma16(wa10, ones, den[1]);
        den[1] = mfma16(wa11, ones, den[1]);
        #pragma unroll
        for (int nt = 0; nt < 4; ++nt) {
            const unsigned short* vp = &Vs[(nt * 16 + ln) * KSTR + lq * 8];
            bf16x8 v0 = *(const bf16x8*)vp, v1 = *(const bf16x8*)(vp + 32);
            num[0][nt] = mfma16(wa00, v0, num[0][nt]);
            num[0][nt] = mfma16(wa01, v1, num[0][nt]);
            num[1][nt] = mfma16(wa10, v0, num[1][nt]);
            num[1][nt] = mfma16(wa11, v1, num[1][nt]);
        }
    }

    // epilogue: partial sums to this half's buffers (disjoint across blocks)
    const size_t noff = (size_t)th * ROWS * HIDN;
    #pragma unroll
    for (int hs = 0; hs < 2; ++hs) {
        #pragma unroll
        for (int r = 0; r < 4; ++r) {
            int s = m0 + hs * 16 + lq * 4 + r;
            #pragma unroll
            for (int nt = 0; nt < 4; ++nt)
                numb[noff + ((size_t)(b * SEQ + s)) * HIDN + h * HD + nt * 16 + ln] =
                    num[hs][nt][r];
            if (ln == 0)
                denb[(size_t)th * BH * SEQ + (size_t)bh * SEQ + s] = den[hs][r];
        }
    }
}

// ------- ctx = f16((num0+num1) / max(den0+den1, eps)) -----------------------
__global__ __launch_bounds__(256)
void finalize_ctx(const float* __restrict__ numb, const float* __restrict__ denb,
                  f16* __restrict__ ctx)
{
    size_t i = ((size_t)blockIdx.x * 256 + threadIdx.x) * 8;
    int row = (int)(i >> 10);               // / HIDN
    int cidx = (int)(i & (HIDN - 1));
    int b = row >> 11, s = row & 2047;
    int h = cidx >> 6;
    size_t di = (size_t)(b * NH + h) * SEQ + s;
    float d = denb[di] + denb[(size_t)BH * SEQ + di];
    float inv = 1.0f / fmaxf(d, 1e-12f);
    const float* n1 = numb + (size_t)ROWS * HIDN;
    float4 a0 = *(const float4*)&numb[i];
    float4 a1 = *(const float4*)&numb[i + 4];
    float4 b0 = *(const float4*)&n1[i];
    float4 b1 = *(const float4*)&n1[i + 4];
    f16x8 o = { (f16)((a0.x + b0.x) * inv), (f16)((a0.y + b0.y) * inv),
                (f16)((a0.z + b0.z) * inv), (f16)((a0.w + b0.w) * inv),
                (f16)((a1.x + b1.x) * inv), (f16)((a1.y + b1.y) * inv),
                (f16)((a1.z + b1.z) * inv), (f16)((a1.w + b1.w) * inv) };
    *(f16x8*)(ctx + i) = o;
}

extern "C" void kernel_launch(void* const* d_in, const int* in_sizes, int n_in,
                              void* d_out, int out_size, void* d_ws, size_t ws_size,
                              hipStream_t stream) {
    const float* x      = (const float*)d_in[0];
    const float* qkv_w  = (const float*)d_in[1];
    const float* qkv_b  = (const float*)d_in[2];
    const float* out_w  = (const float*)d_in[3];
    const float* out_b  = (const float*)d_in[4];
    float* out = (float*)d_out;

    const size_t NTT = (size_t)BH * SEQ * HD;             // 4.19M
    float* qkv = (float*)d_ws;                            // 12.58M f32 region
    // partial buffers live in the (now otherwise unused) qkv region:
    float* colp = qkv;                                    // 4 * BH*SEQ
    float* denb = qkv + 4 * (size_t)BH * SEQ;             // 2 * BH*SEQ
    float* numb = qkv + 6 * (size_t)BH * SEQ;             // 2 * ROWS*HIDN = 8.39M
    float* col = qkv + (size_t)ROWS * 3 * HIDN;           // holds lcl
    f16* xh    = (f16*)(col + (size_t)BH * SEQ);
    f16* wqh   = xh + (size_t)ROWS * HIDN;
    f16* woh   = wqh + (size_t)3 * HIDN * HIDN;
    f16* ctxh  = woh + (size_t)HIDN * HIDN;
    f16* qfp   = ctxh + (size_t)ROWS * HIDN;
    f16* kfp   = qfp + NTT;
    unsigned short* vth = (unsigned short*)(kfp + NTT);

    conv_f16<<<ROWS*HIDN/2048, 256, 0, stream>>>(x, xh);
    conv_f16<<<3*HIDN*HIDN/2048, 256, 0, stream>>>(qkv_w, wqh);
    conv_f16<<<HIDN*HIDN/2048, 256, 0, stream>>>(out_w, woh);

    gemm_qkv_f16<<<dim3(ROWS/128, 3*HIDN/128), 256, 0, stream>>>(
        xh, wqh, qkv_b, qfp, kfp, vth);
    col_sum_f16<<<dim3(SEQ/128, BH, 4), 256, 0, stream>>>(qfp, kfp, colp);
    col_finalize<<<BH*SEQ/1024, 256, 0, stream>>>(colp, col);
    attn_f16<<<dim3(SEQ/128, BH, 2), 256, 0, stream>>>(qfp, kfp, vth, col,
                                                       numb, denb);
    finalize_ctx<<<ROWS*HIDN/2048, 256, 0, stream>>>(numb, denb, ctxh);
    gemm_nt_f16<<<dim3(ROWS/128, HIDN/128), 256, 0, stream>>>(
        ctxh, woh, out_b, out, ROWS, HIDN, HIDN);
}